// Round 12
// baseline (446.386 us; speedup 1.0000x reference)
//
#include <hip/hip_runtime.h>

#define HID 128
#define BR  128        // GEMM rows per block
#define FILL_CHUNK 2048

typedef _Float16 f16;
typedef f16 f16x2 __attribute__((ext_vector_type(2)));
typedef f16 f16x4 __attribute__((ext_vector_type(4)));
typedef f16 f16x8 __attribute__((ext_vector_type(8)));
typedef float f32x4 __attribute__((ext_vector_type(4)));

static __device__ __forceinline__ float2 h2f(unsigned int u) {
    f16x2 v;
    __builtin_memcpy(&v, &u, 4);
    return make_float2((float)v[0], (float)v[1]);
}

// ================= degree / CSR build =================

// 1x edge stream; atomics privatized into per-slice count arrays (slice = blockIdx&7,
// which the round-robin dispatch heuristic pins to one XCD -> L2-resident 400 KB).
// Correct regardless of the mapping (device-scope atomics); mapping only affects speed.
__global__ void k_deg_count(const int* __restrict__ col, int* __restrict__ cnt8, int E, int N) {
    int* cnt = cnt8 + (size_t)(blockIdx.x & 7) * N;
    const int eend = min(E, (blockIdx.x + 1) * FILL_CHUNK);
    for (int e = blockIdx.x * FILL_CHUNK + threadIdx.x; e < eend; e += 256)
        atomicAdd(&cnt[__builtin_nontemporal_load(col + e)], 1);
}

// sums the 8 count slices, emits dinv, then block-exclusive scan
__global__ void k_scan_block(const int* __restrict__ cnt8, int* __restrict__ excl,
                             int* __restrict__ bsum, float* __restrict__ dinv, int N) {
    __shared__ int s[256];
    int i = blockIdx.x * 256 + threadIdx.x;
    int v = 0;
    if (i < N) {
#pragma unroll
        for (int x = 0; x < 8; ++x) v += cnt8[(size_t)x * N + i];
        dinv[i] = 1.0f / sqrtf((float)(v + 1));   // +1 = self-loop
    }
    s[threadIdx.x] = v;
    __syncthreads();
    for (int off = 1; off < 256; off <<= 1) {
        int t = (threadIdx.x >= off) ? s[threadIdx.x - off] : 0;
        __syncthreads();
        s[threadIdx.x] += t;
        __syncthreads();
    }
    if (i < N) excl[i] = s[threadIdx.x] - v;
    if (threadIdx.x == 255) bsum[blockIdx.x] = s[255];
}

__global__ __launch_bounds__(1024) void k_scan_bsum(int* __restrict__ bsum, int nb) {
    __shared__ int s[1024];
    int i = threadIdx.x;
    int v = (i < nb) ? bsum[i] : 0;
    s[i] = v;
    __syncthreads();
    for (int off = 1; off < 1024; off <<= 1) {
        int t = (i >= off) ? s[i - off] : 0;
        __syncthreads();
        s[i] += t;
        __syncthreads();
    }
    if (i < nb) bsum[i] = s[i] - v;
}

__global__ void k_scan_add(int* __restrict__ row_ptr, const int* __restrict__ bsum,
                           int* __restrict__ fill, int N, int E) {
    int i = blockIdx.x * 256 + threadIdx.x;
    if (i < N) {
        int v = row_ptr[i] + bsum[blockIdx.x];
        row_ptr[i] = v;
        fill[i] = v;
    }
    if (i == 0) row_ptr[N] = E;
}

// XCD-range-filtered scatter; NT streaming loads keep L2 free for the dirty
// csr_src window (partially-filled lines must survive until all 16 entries land).
__global__ void k_fill(const int* __restrict__ row, const int* __restrict__ col,
                       int* __restrict__ fill, int* __restrict__ csr_src, int E, int N) {
    const int xcd = blockIdx.x & 7;
    const int chunk = blockIdx.x >> 3;
    const int per = (N + 7) >> 3;
    const int lo = xcd * per;
    const int hi = min(N, lo + per);
    const int eend = min(E, (chunk + 1) * FILL_CHUNK);
    for (int e = chunk * FILL_CHUNK + threadIdx.x; e < eend; e += 256) {
        int c = __builtin_nontemporal_load(col + e);
        if (c >= lo && c < hi) {
            int p = atomicAdd(&fill[c], 1);
            csr_src[p] = __builtin_nontemporal_load(row + e);
        }
    }
}

// ================= W prep (all 3 layers, one launch) =================
// element (k,n) -> (k>>3)*1024 + n*8 + (k&7); hi [0,16384), lo [16384,32768)

__global__ void k_wprep3(const float* __restrict__ W0, const float* __restrict__ W1,
                         const float* __restrict__ W2, f16* __restrict__ out) {
    const int b = blockIdx.x;              // 48 blocks
    const int which = b >> 4;
    const float* W = which == 0 ? W0 : (which == 1 ? W1 : W2);
    f16* o = out + which * 32768;
    int i = (b & 15) * 256 + threadIdx.x;  // 4096 float4s
    int k = i >> 5, n0 = (i & 31) * 4;
    float4 v = reinterpret_cast<const float4*>(W)[i];
    float vv[4] = {v.x, v.y, v.z, v.w};
#pragma unroll
    for (int e = 0; e < 4; ++e) {
        int n = n0 + e;
        int idx = (k >> 3) * 1024 + n * 8 + (k & 7);
        f16 h = (f16)vv[e];
        o[idx] = h;
        o[16384 + idx] = (f16)(vv[e] - (float)h);
    }
}

// ================= GEMM: H16 = f16( dinv .* (X @ W) ) =================
// Swapped-operand MFMA: D = mfma(A=W^T-frag, B=X-frag); f16x4 epilogue stores.
// MODE 0: f32 input, 3 limbs (Wh*Xh + Wl*Xh + Wh*Xl), 64 KB LDS, swizzle at stage.
// MODE 1: f16 input PRE-SWIZZLED + PRE-RELU'd by agg -> staging is a pure
//         linear 32 KB copy (content already in swizzled layout).

template<int MODE>
__global__ __launch_bounds__(512, 4) void k_gemm(const void* __restrict__ Xv,
                                                 const f16* __restrict__ Wt,
                                                 const float* __restrict__ dinv,
                                                 f16* __restrict__ H, int N) {
    __shared__ f16 Xs[MODE == 0 ? 2 * 16384 : 16384];
    const int t = threadIdx.x;
    const int row0 = blockIdx.x * BR;

    const int w  = t >> 6;
    const int l  = t & 63;
    const int lg = l >> 4;
    const int li = l & 15;
    const int ng = w & 3;           // 0..3 -> n-blocks ng*2, ng*2+1
    const int mg = w >> 2;          // 0..1 -> m-blocks mg*4 .. +3

    // W fragments (A operand), issued before X staging (latency hidden)
    f16x8 Wh[2][4], Wl[2][4];
#pragma unroll
    for (int nb = 0; nb < 2; ++nb) {
        const int ncol = (ng * 2 + nb) * 16 + li;
#pragma unroll
        for (int ks = 0; ks < 4; ++ks) {
            const int idx = (ks * 4 + lg) * 1024 + ncol * 8;
            Wh[nb][ks] = *reinterpret_cast<const f16x8*>(&Wt[idx]);
            Wl[nb][ks] = *reinterpret_cast<const f16x8*>(&Wt[16384 + idx]);
        }
    }

    if constexpr (MODE == 0) {
        // f32 input: hi/lo split, 16B-chunk swizzle
        const float* X = (const float*)Xv;
        for (int i = t; i < 4096; i += 512) {
            int r = i >> 5, q = i & 31;
            int gr = row0 + r;
            float4 v = make_float4(0.f, 0.f, 0.f, 0.f);
            if (gr < N) v = reinterpret_cast<const float4*>(X + (size_t)gr * HID)[q];
            f16 h0 = (f16)v.x, h1 = (f16)v.y, h2 = (f16)v.z, h3 = (f16)v.w;
            f16 l0 = (f16)(v.x - (float)h0), l1 = (f16)(v.y - (float)h1);
            f16 l2 = (f16)(v.z - (float)h2), l3 = (f16)(v.w - (float)h3);
            int base = r * 128 + (((q >> 1) ^ (r & 7)) * 8) + (q & 1) * 4;
            *reinterpret_cast<f16x4*>(&Xs[base])         = (f16x4){h0, h1, h2, h3};
            *reinterpret_cast<f16x4*>(&Xs[16384 + base]) = (f16x4){l0, l1, l2, l3};
        }
    } else {
        // f16 input already relu'd + swizzled: straight 32 KB copy (16 B/thread x 4).
        const f16* src = (const f16*)Xv + (size_t)row0 * HID;
        for (int i = t; i < 2048; i += 512)
            *reinterpret_cast<f16x8*>(&Xs[i * 8]) = *reinterpret_cast<const f16x8*>(src + (size_t)i * 8);
    }
    __syncthreads();

    f32x4 acc[2][4];
#pragma unroll
    for (int nb = 0; nb < 2; ++nb)
#pragma unroll
        for (int mb = 0; mb < 4; ++mb) acc[nb][mb] = (f32x4){0.f, 0.f, 0.f, 0.f};

#pragma unroll
    for (int mb = 0; mb < 4; ++mb) {
        const int arow = mg * 64 + mb * 16 + li;
#pragma unroll
        for (int ks = 0; ks < 4; ++ks) {
            const int idx = arow * 128 + (((ks * 4 + lg) ^ (arow & 7)) * 8);
            f16x8 Xh = *reinterpret_cast<const f16x8*>(&Xs[idx]);
#pragma unroll
            for (int nb = 0; nb < 2; ++nb) {
                acc[nb][mb] = __builtin_amdgcn_mfma_f32_16x16x32_f16(Wh[nb][ks], Xh, acc[nb][mb], 0, 0, 0);
                acc[nb][mb] = __builtin_amdgcn_mfma_f32_16x16x32_f16(Wl[nb][ks], Xh, acc[nb][mb], 0, 0, 0);
            }
            if constexpr (MODE == 0) {
                f16x8 Xl = *reinterpret_cast<const f16x8*>(&Xs[16384 + idx]);
#pragma unroll
                for (int nb = 0; nb < 2; ++nb)
                    acc[nb][mb] = __builtin_amdgcn_mfma_f32_16x16x32_f16(Wh[nb][ks], Xl, acc[nb][mb], 0, 0, 0);
            }
        }
    }

    // epilogue: D col(lane&15) = m-offset, row(lg*4+reg) = n-offset -> f16x4 stores
#pragma unroll
    for (int mb = 0; mb < 4; ++mb) {
        const int m = row0 + mg * 64 + mb * 16 + li;
        if (m < N) {
            const float d = dinv[m];
#pragma unroll
            for (int nb = 0; nb < 2; ++nb) {
                f16x4 o = {(f16)(acc[nb][mb][0] * d), (f16)(acc[nb][mb][1] * d),
                           (f16)(acc[nb][mb][2] * d), (f16)(acc[nb][mb][3] * d)};
                *reinterpret_cast<f16x4*>(&H[(size_t)m * HID + (ng * 2 + nb) * 16 + lg * 4]) = o;
            }
        }
    }
}

// ================= aggregation (row-gather, 4 nodes/wave, unroll 8) =================
// 16 lanes per node; lane owns uint4 (8 cols) -> 4 independent chains per wave,
// 32 outstanding 16 B gathers. F16OUT: store relu'd, LDS-swizzled f16 activation
// (consumed by gemm<1> as a linear copy); else plain f32 final output.

template<bool F16OUT>
__global__ __launch_bounds__(256) void k_agg_csr(const f16* __restrict__ h,
                                                 const int* __restrict__ csr_src,
                                                 const int* __restrict__ row_ptr,
                                                 const float* __restrict__ dinv,
                                                 const float* __restrict__ bias,
                                                 void* __restrict__ outv, int N) {
    const int node = blockIdx.x * 16 + (threadIdx.x >> 4);
    if (node >= N) return;
    const int l = threadIdx.x & 15;
    const uint4* h4 = reinterpret_cast<const uint4*>(h);   // row = 16 uint4

    uint4 us = h4[(size_t)node * 16 + l];
    float2 a0 = h2f(us.x), a1 = h2f(us.y), a2 = h2f(us.z), a3 = h2f(us.w);
    float acc0 = a0.x, acc1 = a0.y, acc2 = a1.x, acc3 = a1.y;
    float acc4 = a2.x, acc5 = a2.y, acc6 = a3.x, acc7 = a3.y;

    int j = row_ptr[node];
    const int end = row_ptr[node + 1];

    for (; j + 8 <= end; j += 8) {
        int s0 = __builtin_nontemporal_load(csr_src + j);
        int s1 = __builtin_nontemporal_load(csr_src + j + 1);
        int s2 = __builtin_nontemporal_load(csr_src + j + 2);
        int s3 = __builtin_nontemporal_load(csr_src + j + 3);
        int s4 = __builtin_nontemporal_load(csr_src + j + 4);
        int s5 = __builtin_nontemporal_load(csr_src + j + 5);
        int s6 = __builtin_nontemporal_load(csr_src + j + 6);
        int s7 = __builtin_nontemporal_load(csr_src + j + 7);
        uint4 u0 = h4[(size_t)s0 * 16 + l];
        uint4 u1 = h4[(size_t)s1 * 16 + l];
        uint4 u2 = h4[(size_t)s2 * 16 + l];
        uint4 u3 = h4[(size_t)s3 * 16 + l];
        uint4 u4 = h4[(size_t)s4 * 16 + l];
        uint4 u5 = h4[(size_t)s5 * 16 + l];
        uint4 u6 = h4[(size_t)s6 * 16 + l];
        uint4 u7 = h4[(size_t)s7 * 16 + l];
#pragma unroll
        for (int q = 0; q < 1; ++q) { }   // (keeps structure flat)
        float2 t;
        t = h2f(u0.x); acc0 += t.x; acc1 += t.y;  t = h2f(u0.y); acc2 += t.x; acc3 += t.y;
        t = h2f(u0.z); acc4 += t.x; acc5 += t.y;  t = h2f(u0.w); acc6 += t.x; acc7 += t.y;
        t = h2f(u1.x); acc0 += t.x; acc1 += t.y;  t = h2f(u1.y); acc2 += t.x; acc3 += t.y;
        t = h2f(u1.z); acc4 += t.x; acc5 += t.y;  t = h2f(u1.w); acc6 += t.x; acc7 += t.y;
        t = h2f(u2.x); acc0 += t.x; acc1 += t.y;  t = h2f(u2.y); acc2 += t.x; acc3 += t.y;
        t = h2f(u2.z); acc4 += t.x; acc5 += t.y;  t = h2f(u2.w); acc6 += t.x; acc7 += t.y;
        t = h2f(u3.x); acc0 += t.x; acc1 += t.y;  t = h2f(u3.y); acc2 += t.x; acc3 += t.y;
        t = h2f(u3.z); acc4 += t.x; acc5 += t.y;  t = h2f(u3.w); acc6 += t.x; acc7 += t.y;
        t = h2f(u4.x); acc0 += t.x; acc1 += t.y;  t = h2f(u4.y); acc2 += t.x; acc3 += t.y;
        t = h2f(u4.z); acc4 += t.x; acc5 += t.y;  t = h2f(u4.w); acc6 += t.x; acc7 += t.y;
        t = h2f(u5.x); acc0 += t.x; acc1 += t.y;  t = h2f(u5.y); acc2 += t.x; acc3 += t.y;
        t = h2f(u5.z); acc4 += t.x; acc5 += t.y;  t = h2f(u5.w); acc6 += t.x; acc7 += t.y;
        t = h2f(u6.x); acc0 += t.x; acc1 += t.y;  t = h2f(u6.y); acc2 += t.x; acc3 += t.y;
        t = h2f(u6.z); acc4 += t.x; acc5 += t.y;  t = h2f(u6.w); acc6 += t.x; acc7 += t.y;
        t = h2f(u7.x); acc0 += t.x; acc1 += t.y;  t = h2f(u7.y); acc2 += t.x; acc3 += t.y;
        t = h2f(u7.z); acc4 += t.x; acc5 += t.y;  t = h2f(u7.w); acc6 += t.x; acc7 += t.y;
    }
    for (; j < end; ++j) {
        int s = __builtin_nontemporal_load(csr_src + j);
        uint4 u = h4[(size_t)s * 16 + l];
        float2 t;
        t = h2f(u.x); acc0 += t.x; acc1 += t.y;  t = h2f(u.y); acc2 += t.x; acc3 += t.y;
        t = h2f(u.z); acc4 += t.x; acc5 += t.y;  t = h2f(u.w); acc6 += t.x; acc7 += t.y;
    }

    const float di = dinv[node];
    const float4 bv0 = reinterpret_cast<const float4*>(bias)[l * 2];
    const float4 bv1 = reinterpret_cast<const float4*>(bias)[l * 2 + 1];
    float o0 = fmaf(di, acc0, bv0.x), o1 = fmaf(di, acc1, bv0.y);
    float o2 = fmaf(di, acc2, bv0.z), o3 = fmaf(di, acc3, bv0.w);
    float o4 = fmaf(di, acc4, bv1.x), o5 = fmaf(di, acc5, bv1.y);
    float o6 = fmaf(di, acc6, bv1.z), o7 = fmaf(di, acc7, bv1.w);

    if constexpr (F16OUT) {
        // relu + swizzled 16B store: chunk l -> chunk l ^ (node&7)
        f16x8 o = {(f16)fmaxf(o0, 0.f), (f16)fmaxf(o1, 0.f), (f16)fmaxf(o2, 0.f),
                   (f16)fmaxf(o3, 0.f), (f16)fmaxf(o4, 0.f), (f16)fmaxf(o5, 0.f),
                   (f16)fmaxf(o6, 0.f), (f16)fmaxf(o7, 0.f)};
        *reinterpret_cast<f16x8*>((f16*)outv + (size_t)node * HID + (l ^ (node & 7)) * 8) = o;
    } else {
        float* op = (float*)outv + (size_t)node * HID + l * 8;
        *reinterpret_cast<float4*>(op)     = make_float4(o0, o1, o2, o3);
        *reinterpret_cast<float4*>(op + 4) = make_float4(o4, o5, o6, o7);
    }
}

// ================= launch =================

extern "C" void kernel_launch(void* const* d_in, const int* in_sizes, int n_in,
                              void* d_out, int out_size, void* d_ws, size_t ws_size,
                              hipStream_t stream) {
    const float* x  = (const float*)d_in[0];
    const int*   ei = (const int*)  d_in[1];
    const float* W0 = (const float*)d_in[2];
    const float* b0 = (const float*)d_in[3];
    const float* W1 = (const float*)d_in[4];
    const float* b1 = (const float*)d_in[5];
    const float* W2 = (const float*)d_in[6];
    const float* b2 = (const float*)d_in[7];

    const int N = in_sizes[0] / HID;
    const int E = in_sizes[1] / 2;
    const int* row = ei;        // sources
    const int* col = ei + E;    // destinations

    const int nb_n = (N + 255) / 256;

    // workspace layout
    f16*   h16     = (f16*)d_ws;                      // [N,128] f16 (= h', dinv-scaled)
    float* dinv    = (float*)(h16 + (size_t)N * HID); // [N]
    int*   cnt8    = (int*)(dinv + N);                // [8][N]
    int*   row_ptr = cnt8 + (size_t)8 * N;            // [N+1]
    int*   fill    = row_ptr + (N + 1);               // [N]
    int*   bsum    = fill + N;                        // [nb_n]
    int*   csr_src = bsum + nb_n;                     // [E]
    f16*   wt      = (f16*)(csr_src + E);             // [3*32768]
    f16*   wt0     = wt;
    f16*   wt1     = wt + 32768;
    f16*   wt2     = wt + 65536;
    f16*   act     = (f16*)d_out;                     // layers 0,1 activation (f16, swizzled, relu'd)
    float* out     = (float*)d_out;                   // final f32 output

    const int nb_gemm  = (N + BR - 1) / BR;
    const int nb_agg   = (N + 15) / 16;               // 4 nodes per wave
    const int nb_chunk = (E + FILL_CHUNK - 1) / FILL_CHUNK;
    const int nb_fill  = nb_chunk * 8;

    // ---- CSR build + W prep ----
    hipMemsetAsync(cnt8, 0, (size_t)8 * N * sizeof(int), stream);
    k_wprep3<<<48, 256, 0, stream>>>(W0, W1, W2, wt);
    k_deg_count <<<nb_chunk, 256, 0, stream>>>(col, cnt8, E, N);
    k_scan_block<<<nb_n, 256, 0, stream>>>(cnt8, row_ptr, bsum, dinv, N);
    k_scan_bsum <<<1, 1024, 0, stream>>>(bsum, nb_n);
    k_scan_add  <<<nb_n, 256, 0, stream>>>(row_ptr, bsum, fill, N, E);
    k_fill      <<<nb_fill, 256, 0, stream>>>(row, col, fill, csr_src, E, N);

    // ---- layer 0: x (f32) -> h16 -> act (f16, swizzled+relu) ----
    k_gemm<0>      <<<nb_gemm, 512, 0, stream>>>(x, wt0, dinv, h16, N);
    k_agg_csr<true><<<nb_agg, 256, 0, stream>>>(h16, csr_src, row_ptr, dinv, b0, act, N);
    // ---- layer 1: act -> h16 -> act ----
    k_gemm<1>      <<<nb_gemm, 512, 0, stream>>>(act, wt1, dinv, h16, N);
    k_agg_csr<true><<<nb_agg, 256, 0, stream>>>(h16, csr_src, row_ptr, dinv, b1, act, N);
    // ---- layer 2: act -> h16 -> out (f32) ----
    k_gemm<1>      <<<nb_gemm, 512, 0, stream>>>(act, wt2, dinv, h16, N);
    k_agg_csr<false><<<nb_agg, 256, 0, stream>>>(h16, csr_src, row_ptr, dinv, b2, out, N);
}